// Round 4
// baseline (556.320 us; speedup 1.0000x reference)
//
#include <hip/hip_runtime.h>
#include <hip/hip_bf16.h>
#include <stdint.h>

#define NN 8192
#define GG 512
#define HH 512
#define LL 64
#define TOPK 9                 // K+1 = 9 (incl. self, self weight zeroed)
#define NEDGE (NN*TOPK)        // 73728 directed edges
#define NNZ (2*NEDGE)          // 147456 CSR entries after symmetrization

typedef unsigned long long u64;
typedef unsigned int u32;
typedef unsigned short u16;

struct InPtrs { const void* p[12]; };

__device__ __forceinline__ float bf2f(u16 u) { return __uint_as_float(((u32)u) << 16); }
__device__ __forceinline__ u16 f2bf(float f) {
  u32 x = __float_as_uint(f);
  u32 r = x + 0x7fffu + ((x >> 16) & 1u);   // RNE
  return (u16)(r >> 16);
}

// ---------------- dtype detection ----------------
__global__ void k_detect(const void* coords_raw, int* flag) {
  if (threadIdx.x != 0 || blockIdx.x != 0) return;
  const u16* u = (const u16*)coords_raw;
  int ok = 1;
  for (int t = 0; t < 64; ++t) {
    float v = bf2f(u[t]);
    if (!(v >= -0.01f && v <= 1.02f)) ok = 0;
  }
  *flag = ok;  // 1 = bf16 inputs/outputs, 0 = fp32
}

// ---------------- upconvert all 12 inputs to fp32 in ws ----------------
__global__ void k_convert(InPtrs in, const int* __restrict__ flag, float* __restrict__ dst) {
  const int sizes[12] = {NN*GG, NN*2, HH*GG, HH, HH*2, HH, HH*HH, HH, HH*HH, HH, LL*HH, LL};
  const int TOTAL = 5033024;
  int isbf = *flag;
  for (int e = blockIdx.x * blockDim.x + threadIdx.x; e < TOTAL; e += gridDim.x * blockDim.x) {
    int base = 0;
#pragma unroll
    for (int s = 0; s < 12; ++s) {
      if (e < base + sizes[s]) {
        int loc = e - base;
        dst[e] = isbf ? bf2f(((const u16*)in.p[s])[loc]) : ((const float*)in.p[s])[loc];
        break;
      }
      base += sizes[s];
    }
  }
}

// ---------------- sq[j] = round(round(x*x) + round(y*y)) — np.sum(c*c,axis=1), NO fma ----------------
__global__ void k_sq(const float* __restrict__ coords, float* __restrict__ sq) {
  int j = blockIdx.x * blockDim.x + threadIdx.x;
  if (j < NN) {
    float x = coords[2*j], y = coords[2*j+1];
    sq[j] = __fadd_rn(__fmul_rn(x, x), __fmul_rn(y, y));
  }
}

// ---------------- KNN top-9 per row: bit-faithful np float32 expansion form ----------------
// np: sq = sum(c*c,1); d2 = sq[:,None]+sq[None,:]-2*(c@c.T); d = sqrt(max(d2,0))
// BLAS sgemm k-order dot: fma(y_i, y_j, round(x_i*x_j)).
// Selection: 9 smallest by (d_bits, j) lexicographic (stable top_k, lower index ties).
// Weight: exp(-(d*d)/2.0f), self zeroed.
__global__ __launch_bounds__(256) void k_knn(const float* __restrict__ coords,
                                             const float* __restrict__ sq,
                                             int* __restrict__ eidx, float* __restrict__ ew) {
  const int wid = threadIdx.x >> 6, lane = threadIdx.x & 63;
  const int i = blockIdx.x * 4 + wid;
  const float2* c2 = (const float2*)coords;
  const float2 cif = c2[i];
  const float cix = cif.x, ciy = cif.y;
  const float sqi = sq[i];

  u64 arr[TOPK];
#pragma unroll
  for (int q = 0; q < TOPK; ++q) arr[q] = ~0ULL;
  u64 curmax = ~0ULL; int maxpos = 0;

  for (int c = 0; c < NN / 64; ++c) {
    int j = c * 64 + lane;
    float2 cjf = c2[j];
    // BLAS k-order: k=0 (x) product rounded, k=1 (y) fused on top
    float dot = __fmaf_rn(ciy, cjf.y, __fmul_rn(cix, cjf.x));
    float d2  = __fsub_rn(__fadd_rn(sqi, sq[j]), __fmul_rn(2.0f, dot));
    float d   = __fsqrt_rn(fmaxf(d2, 0.0f));
    u64 pack = ((u64)__float_as_uint(d) << 32) | (u32)j;
    if (pack < curmax) {
      arr[maxpos] = pack;
      curmax = 0;
#pragma unroll
      for (int q = 0; q < TOPK; ++q) if (arr[q] >= curmax) { curmax = arr[q]; maxpos = q; }
    }
  }

  // 9 rounds of global-min extraction across the wave (packs unique: j unique)
  for (int r = 0; r < TOPK; ++r) {
    u64 lm = ~0ULL; int lp = 0;
#pragma unroll
    for (int q = 0; q < TOPK; ++q) if (arr[q] < lm) { lm = arr[q]; lp = q; }
    u64 g = lm;
#pragma unroll
    for (int o = 32; o > 0; o >>= 1) {
      u64 other = __shfl_xor(g, o, 64);
      if (other < g) g = other;
    }
    if (lm == g) arr[lp] = ~0ULL;   // exactly one owning lane
    if (lane == 0) {
      u32 dbits = (u32)(g >> 32);
      int j = (int)(g & 0xffffffffu);
      float d = __uint_as_float(dbits);
      float w = (j == i) ? 0.0f : expf(__fdiv_rn(-__fmul_rn(d, d), 2.0f));
      eidx[i * TOPK + r] = j;
      ew[i * TOPK + r] = w;
    }
  }
}

// ---------------- degree: deg[i] = sum_j A_sym[i][j] ----------------
__global__ void k_deg(const int* __restrict__ eidx, const float* __restrict__ ew,
                      float* __restrict__ deg) {
  int t = blockIdx.x * blockDim.x + threadIdx.x;
  if (t >= NEDGE) return;
  int i = t / TOPK;
  int j = eidx[t];
  float h = 0.5f * ew[t];
  atomicAdd(&deg[i], h);
  atomicAdd(&deg[j], h);
}

__global__ void k_dis(const float* __restrict__ deg, float* __restrict__ dis) {
  int i = blockIdx.x * blockDim.x + threadIdx.x;
  if (i < NN) dis[i] = 1.0f / sqrtf(deg[i] + 1e-8f);
}

// ---------------- CSR build ----------------
__global__ void k_cnt(const int* __restrict__ eidx, int* __restrict__ cnt) {
  int t = blockIdx.x * blockDim.x + threadIdx.x;
  if (t >= NEDGE) return;
  int i = t / TOPK;
  int j = eidx[t];
  atomicAdd(&cnt[i], 1);
  atomicAdd(&cnt[j], 1);
}

__global__ __launch_bounds__(1024) void k_scan(const int* __restrict__ cnt,
                                               int* __restrict__ rs, int* __restrict__ cur) {
  __shared__ int part[1024];
  int t = threadIdx.x;
  int base = t * 8;
  int loc[8]; int s = 0;
#pragma unroll
  for (int q = 0; q < 8; ++q) { loc[q] = s; s += cnt[base + q]; }
  part[t] = s;
  __syncthreads();
  for (int o = 1; o < 1024; o <<= 1) {
    int v = 0;
    if (t >= o) v = part[t - o];
    __syncthreads();
    part[t] += v;
    __syncthreads();
  }
  int excl = (t == 0) ? 0 : part[t - 1];
#pragma unroll
  for (int q = 0; q < 8; ++q) {
    int val = excl + loc[q];
    rs[base + q] = val;
    cur[base + q] = val;
  }
  if (t == 1023) rs[NN] = excl + s;
}

__global__ void k_fill(const int* __restrict__ eidx, const float* __restrict__ ew,
                       int* __restrict__ cur, int* __restrict__ ccol, float* __restrict__ cw) {
  int t = blockIdx.x * blockDim.x + threadIdx.x;
  if (t >= NEDGE) return;
  int i = t / TOPK;
  int j = eidx[t];
  float h = 0.5f * ew[t];
  int s1 = atomicAdd(&cur[i], 1); ccol[s1] = j; cw[s1] = h;
  int s2 = atomicAdd(&cur[j], 1); ccol[s2] = i; cw[s2] = h;
}

// ---------------- agg = A_norm @ h  (one block per row) ----------------
__global__ __launch_bounds__(256) void k_agg(const int* __restrict__ rs, const int* __restrict__ ccol,
                                             const float* __restrict__ cw, const float* __restrict__ dis,
                                             const float* __restrict__ h, float* __restrict__ agg) {
  int i = blockIdx.x, t = threadIdx.x;
  int b = rs[i], e = rs[i + 1];
  float di = dis[i];
  float s0 = 0.f, s1 = 0.f;
  for (int q = b; q < e; ++q) {
    int c = ccol[q];
    float w = cw[q] * dis[c];
    s0 = fmaf(w, h[c * HH + t], s0);
    s1 = fmaf(w, h[c * HH + t + 256], s1);
  }
  agg[i * HH + t] = di * s0;
  agg[i * HH + t + 256] = di * s1;
}

// ---------------- GEMM: C = A[8192,512] * W[rows,512]^T, fp32, 64x64x32 tiles ----------------
// MODE 0: h = relu(acc + b_g1) + relu(coords-gemm)    (aux0=coords, aux1=W_c1, aux2=b_c1)
// MODE 1: relu(acc + b)
// MODE 2: relu(relu(acc + b) + aux0[msg])  (element-wise in-place safe)
// MODE 3: acc + b -> d_out (dtype per flag)
template <int MODE>
__global__ __launch_bounds__(256) void k_gemm(const float* __restrict__ A, const float* __restrict__ W,
                                              const float* __restrict__ bias, const float* __restrict__ aux0,
                                              const float* __restrict__ aux1, const float* __restrict__ aux2,
                                              const int* __restrict__ flag, void* __restrict__ outp, int ldc) {
  __shared__ float As[32][68];   // [BK][BM+4]
  __shared__ float Bs[32][68];
  const int tx = threadIdx.x & 15, ty = threadIdx.x >> 4;
  const int row0 = blockIdx.y * 64, col0 = blockIdx.x * 64;
  const int lr = threadIdx.x >> 3;          // 0..31
  const int lk = (threadIdx.x & 7) << 2;    // 0,4,...,28
  float acc[4][4] = {};
  const float* Ap = A + (size_t)(row0 + lr) * 512 + lk;
  const float* Wp = W + (size_t)(col0 + lr) * 512 + lk;

  for (int kk = 0; kk < 512; kk += 32) {
    float4 a0 = *(const float4*)(Ap + kk);
    float4 a1 = *(const float4*)(Ap + kk + 32 * 512);
    float4 b0 = *(const float4*)(Wp + kk);
    float4 b1 = *(const float4*)(Wp + kk + 32 * 512);
    __syncthreads();
    As[lk+0][lr] = a0.x; As[lk+1][lr] = a0.y; As[lk+2][lr] = a0.z; As[lk+3][lr] = a0.w;
    As[lk+0][lr+32] = a1.x; As[lk+1][lr+32] = a1.y; As[lk+2][lr+32] = a1.z; As[lk+3][lr+32] = a1.w;
    Bs[lk+0][lr] = b0.x; Bs[lk+1][lr] = b0.y; Bs[lk+2][lr] = b0.z; Bs[lk+3][lr] = b0.w;
    Bs[lk+0][lr+32] = b1.x; Bs[lk+1][lr+32] = b1.y; Bs[lk+2][lr+32] = b1.z; Bs[lk+3][lr+32] = b1.w;
    __syncthreads();
#pragma unroll
    for (int k2 = 0; k2 < 32; ++k2) {
      float4 av = *(const float4*)(&As[k2][ty << 2]);
      float4 bv = *(const float4*)(&Bs[k2][tx << 2]);
      float am[4] = {av.x, av.y, av.z, av.w};
      float bm[4] = {bv.x, bv.y, bv.z, bv.w};
#pragma unroll
      for (int im = 0; im < 4; ++im)
#pragma unroll
        for (int jn = 0; jn < 4; ++jn)
          acc[im][jn] = fmaf(am[im], bm[jn], acc[im][jn]);
    }
  }

  int flg = (MODE == 3) ? *flag : 0;
#pragma unroll
  for (int im = 0; im < 4; ++im) {
    int r = row0 + (ty << 2) + im;
    float cx = 0.f, cy = 0.f;
    if (MODE == 0) { cx = aux0[2 * r]; cy = aux0[2 * r + 1]; }
#pragma unroll
    for (int jn = 0; jn < 4; ++jn) {
      int c = col0 + (tx << 2) + jn;
      float v = acc[im][jn] + bias[c];
      if (MODE == 0) {
        float hc = cx * aux1[2 * c] + cy * aux1[2 * c + 1] + aux2[c];
        v = fmaxf(v, 0.f) + fmaxf(hc, 0.f);
      } else if (MODE == 1) {
        v = fmaxf(v, 0.f);
      } else if (MODE == 2) {
        v = fmaxf(v, 0.f);
        v = fmaxf(v + aux0[(size_t)r * 512 + c], 0.f);
      }
      if (MODE == 3) {
        if (flg) ((u16*)outp)[(size_t)r * ldc + c] = f2bf(v);
        else     ((float*)outp)[(size_t)r * ldc + c] = v;
      } else {
        ((float*)outp)[(size_t)r * ldc + c] = v;
      }
    }
  }
}

extern "C" void kernel_launch(void* const* d_in, const int* in_sizes, int n_in,
                              void* d_out, int out_size, void* d_ws, size_t ws_size,
                              hipStream_t stream) {
  float* ws = (float*)d_ws;
  size_t off = 0;
  auto alloc = [&](size_t n) { size_t o = off; off += (n + 15) & ~(size_t)15; return o; };

  size_t o_flag = alloc(16);
  size_t o_conv = alloc(5033024);
  size_t o_H    = alloc((size_t)NN * HH);
  size_t o_MSG  = alloc((size_t)NN * HH);
  size_t o_sq   = alloc(NN);
  size_t o_deg  = alloc(NN);
  size_t o_dis  = alloc(NN);
  size_t o_cnt  = alloc(NN);
  size_t o_rs   = alloc(NN + 16);
  size_t o_cur  = alloc(NN);
  size_t o_eidx = alloc(NEDGE);
  size_t o_ew   = alloc(NEDGE);
  size_t o_ccol = alloc(NNZ);
  size_t o_cw   = alloc(NNZ);
  (void)ws_size;

  int*   flag   = (int*)(ws + o_flag);
  float* conv   = ws + o_conv;
  float* geneC  = conv + 0;
  float* coordsC= conv + 4194304;
  float* Wg1    = conv + 4210688;
  float* bg1    = conv + 4472832;
  float* Wc1    = conv + 4473344;
  float* bc1    = conv + 4474368;
  float* Wmsg   = conv + 4474880;
  float* bmsg   = conv + 4737024;
  float* Wself  = conv + 4737536;
  float* bself  = conv + 4999680;
  float* Wz     = conv + 5000192;
  float* bz     = conv + 5032960;
  float* Hbuf   = ws + o_H;
  float* Mbuf   = ws + o_MSG;
  float* AGG    = geneC;            // reuse gene buffer after GEMM1 consumed it
  float* sq     = ws + o_sq;
  float* deg    = ws + o_deg;
  float* dis    = ws + o_dis;
  int*   cnt    = (int*)(ws + o_cnt);
  int*   rs     = (int*)(ws + o_rs);
  int*   cur    = (int*)(ws + o_cur);
  int*   eidx   = (int*)(ws + o_eidx);
  float* ew     = ws + o_ew;
  int*   ccol   = (int*)(ws + o_ccol);
  float* cw     = ws + o_cw;

  InPtrs ip;
  for (int s = 0; s < 12; ++s) ip.p[s] = d_in[s];

  k_detect<<<1, 64, 0, stream>>>(d_in[1], flag);
  k_convert<<<2048, 256, 0, stream>>>(ip, flag, conv);
  k_sq<<<NN / 256, 256, 0, stream>>>(coordsC, sq);
  k_knn<<<NN / 4, 256, 0, stream>>>(coordsC, sq, eidx, ew);
  hipMemsetAsync(deg, 0, NN * 4, stream);
  hipMemsetAsync(cnt, 0, NN * 4, stream);
  k_deg<<<(NEDGE + 255) / 256, 256, 0, stream>>>(eidx, ew, deg);
  k_dis<<<NN / 256, 256, 0, stream>>>(deg, dis);
  k_cnt<<<(NEDGE + 255) / 256, 256, 0, stream>>>(eidx, cnt);
  k_scan<<<1, 1024, 0, stream>>>(cnt, rs, cur);
  k_fill<<<(NEDGE + 255) / 256, 256, 0, stream>>>(eidx, ew, cur, ccol, cw);

  dim3 blk(256);
  k_gemm<0><<<dim3(8, 128), blk, 0, stream>>>(geneC, Wg1, bg1, coordsC, Wc1, bc1, flag, Hbuf, 512);
  k_agg<<<NN, 256, 0, stream>>>(rs, ccol, cw, dis, Hbuf, AGG);
  k_gemm<1><<<dim3(8, 128), blk, 0, stream>>>(AGG, Wmsg, bmsg, nullptr, nullptr, nullptr, flag, Mbuf, 512);
  k_gemm<2><<<dim3(8, 128), blk, 0, stream>>>(Hbuf, Wself, bself, Mbuf, nullptr, nullptr, flag, Mbuf, 512);
  k_gemm<3><<<dim3(1, 128), blk, 0, stream>>>(Mbuf, Wz, bz, nullptr, nullptr, nullptr, flag, d_out, 64);
}